// Round 4
// baseline (504.361 us; speedup 1.0000x reference)
//
#include <hip/hip_runtime.h>
#include <hip/hip_bf16.h>
#include <math.h>

#define N_NODES 50000
#define N_EDGES 800000
#define IN_DIM_ 128
#define OUT_DIM_ 64
#define ALPHA_ 0.2f

#define PSH 6                 // 64 src-nodes per partition
#define PNODES 64
#define NPART 782             // ceil(50000/64)
#define CAPP 2048             // per-partition capacity; mean 1024, +32 sigma
#define BIN_BLOCKS 256
#define BIN_CHUNK ((N_EDGES + BIN_BLOCKS - 1) / BIN_BLOCKS)   // 3125
#define OVF_CAP 8192          // never used in practice; correctness guard

// ---------------------------------------------------------------------------
// Kernel 1: h = x @ W  (M=50000, K=128, N=64) fp32 vector GEMM, with the
// node-score epilogue fused: a_src[n] = h[n]·a[:64], a_dst[n] = h[n]·a[64:].
// ---------------------------------------------------------------------------
__global__ __launch_bounds__(256, 4) void gemm_h(const float* __restrict__ x,
                                                 const float* __restrict__ W,
                                                 const float* __restrict__ a_g,
                                                 float* __restrict__ h,
                                                 float* __restrict__ a_srcv,
                                                 float* __restrict__ a_dstv) {
    __shared__ float At[64][68];  // [kk][row]
    __shared__ float Wl[64][68];  // [kk][col]
    const int tid = threadIdx.x;
    const int tx = tid & 15;      // col group (4 cols)
    const int ty = tid >> 4;      // row group (4 rows)
    const int row0 = blockIdx.x * 64;

    float acc[4][4] = {};

    for (int ks = 0; ks < 128; ks += 64) {
        {
            const int r  = tid >> 4;   // 0..15
            const int k4 = tid & 15;   // float4 index along k
            #pragma unroll
            for (int rr = 0; rr < 64; rr += 16) {
                const int row = row0 + r + rr;
                float4 v = make_float4(0.f, 0.f, 0.f, 0.f);
                if (row < N_NODES)
                    v = *(const float4*)&x[(size_t)row * IN_DIM_ + ks + k4 * 4];
                At[k4 * 4 + 0][r + rr] = v.x;
                At[k4 * 4 + 1][r + rr] = v.y;
                At[k4 * 4 + 2][r + rr] = v.z;
                At[k4 * 4 + 3][r + rr] = v.w;
            }
            const int kr = tid >> 4;
            const int c4 = tid & 15;
            #pragma unroll
            for (int kk = 0; kk < 64; kk += 16) {
                float4 wv = *(const float4*)&W[(size_t)(ks + kr + kk) * OUT_DIM_ + c4 * 4];
                *(float4*)&Wl[kr + kk][c4 * 4] = wv;
            }
        }
        __syncthreads();

        #pragma unroll 16
        for (int kk = 0; kk < 64; ++kk) {
            const float4 a4 = *(const float4*)&At[kk][ty * 4];
            const float4 b4 = *(const float4*)&Wl[kk][tx * 4];
            acc[0][0] += a4.x * b4.x; acc[0][1] += a4.x * b4.y; acc[0][2] += a4.x * b4.z; acc[0][3] += a4.x * b4.w;
            acc[1][0] += a4.y * b4.x; acc[1][1] += a4.y * b4.y; acc[1][2] += a4.y * b4.z; acc[1][3] += a4.y * b4.w;
            acc[2][0] += a4.z * b4.x; acc[2][1] += a4.z * b4.y; acc[2][2] += a4.z * b4.z; acc[2][3] += a4.z * b4.w;
            acc[3][0] += a4.w * b4.x; acc[3][1] += a4.w * b4.y; acc[3][2] += a4.w * b4.z; acc[3][3] += a4.w * b4.w;
        }
        __syncthreads();
    }

    const float a0 = a_g[tx * 4 + 0], a1 = a_g[tx * 4 + 1];
    const float a2 = a_g[tx * 4 + 2], a3 = a_g[tx * 4 + 3];
    const float b0 = a_g[64 + tx * 4 + 0], b1 = a_g[64 + tx * 4 + 1];
    const float b2 = a_g[64 + tx * 4 + 2], b3 = a_g[64 + tx * 4 + 3];

    #pragma unroll
    for (int i = 0; i < 4; ++i) {
        const int row = row0 + ty * 4 + i;
        if (row < N_NODES) {
            float4 o = make_float4(acc[i][0], acc[i][1], acc[i][2], acc[i][3]);
            *(float4*)&h[(size_t)row * OUT_DIM_ + tx * 4] = o;
        }
        float s = acc[i][0] * a0 + acc[i][1] * a1 + acc[i][2] * a2 + acc[i][3] * a3;
        float d = acc[i][0] * b0 + acc[i][1] * b1 + acc[i][2] * b2 + acc[i][3] * b3;
        #pragma unroll
        for (int m = 1; m < 16; m <<= 1) {
            s += __shfl_xor(s, m);
            d += __shfl_xor(d, m);
        }
        if (tx == 0 && row < N_NODES) {
            a_srcv[row] = s;
            a_dstv[row] = d;
        }
    }
}

// ---------------------------------------------------------------------------
// Kernel 2: bin edges by src-partition (64 nodes/partition).
// Per block: LDS histogram (fire-and-forget LDS atomics) -> ONE global
// atomicAdd per non-empty partition to reserve a contiguous range -> place
// each edge via LDS atomic-with-return (cheap) + 4B packed write.
// Packing: entry = (s&63)<<16 | d   (d < 50000 < 2^16).
// ---------------------------------------------------------------------------
__global__ __launch_bounds__(256) void bin_edges(const int* __restrict__ ei,
                                                 int* __restrict__ part_cnt,
                                                 unsigned int* __restrict__ part_buf,
                                                 int* __restrict__ ovf_cnt,
                                                 int2* __restrict__ ovf) {
    __shared__ int hist[NPART];
    __shared__ int cur[NPART];
    const int tid = threadIdx.x;
    const int e0 = blockIdx.x * BIN_CHUNK;
    const int e1 = min(e0 + BIN_CHUNK, N_EDGES);

    for (int p = tid; p < NPART; p += 256) hist[p] = 0;
    __syncthreads();

    for (int e = e0 + tid; e < e1; e += 256) {
        atomicAdd(&hist[ei[e] >> PSH], 1);
    }
    __syncthreads();

    for (int p = tid; p < NPART; p += 256) {
        const int c = hist[p];
        cur[p] = (c > 0) ? atomicAdd(&part_cnt[p], c) : 0;
    }
    __syncthreads();

    for (int e = e0 + tid; e < e1; e += 256) {
        const int s = ei[e];
        const int d = ei[N_EDGES + e];
        const int p = s >> PSH;
        const int slot = atomicAdd(&cur[p], 1);   // LDS rtn atomic: cheap
        if (slot < CAPP) {
            part_buf[(size_t)p * CAPP + slot] =
                ((unsigned)(s & (PNODES - 1)) << 16) | (unsigned)d;
        } else {
            const int o = atomicAdd(ovf_cnt, 1);
            if (o < OVF_CAP) ovf[o] = make_int2(s, d);
        }
    }
}

// ---------------------------------------------------------------------------
// Kernel 3: per-partition gather-accumulate into a 64x64 LDS tile.
// One block (4 waves) per partition. Waves take 64-edge groups: coalesced
// entry load, parallel weight compute per lane, then 64 broadcast steps:
// coalesced 256B gather of h[dst] + fire-and-forget LDS atomicAdd into the
// src row (lane c -> bank c%32: 2 lanes/bank, conflict-free). Z fused.
// One coalesced 16KB store per block. Zero global atomics.
// ---------------------------------------------------------------------------
__global__ __launch_bounds__(256) void gather_accum(const int* __restrict__ part_cnt,
                                                    const unsigned int* __restrict__ part_buf,
                                                    const float* __restrict__ a_srcv,
                                                    const float* __restrict__ a_dstv,
                                                    const float* __restrict__ h,
                                                    float* __restrict__ out,
                                                    float* __restrict__ Z) {
    __shared__ float accs[PNODES][PNODES];   // 16 KB
    __shared__ float asl[PNODES];
    __shared__ float zred[4];
    const int p = blockIdx.x;
    const int tid = threadIdx.x;
    const int lane = tid & 63;
    const int wid = tid >> 6;
    const int n0 = p << PSH;

    float4* az = (float4*)&accs[0][0];
    for (int i = tid; i < PNODES * PNODES / 4; i += 256)
        az[i] = make_float4(0.f, 0.f, 0.f, 0.f);
    if (tid < PNODES)
        asl[tid] = (n0 + tid < N_NODES) ? a_srcv[n0 + tid] : 0.f;
    __syncthreads();

    const int cnt = min(part_cnt[p], CAPP);
    const unsigned int* __restrict__ buf = part_buf + (size_t)p * CAPP;
    float zacc = 0.f;

    for (int g0 = wid * 64; g0 < cnt; g0 += 4 * 64) {
        const int i = g0 + lane;
        const bool valid = i < cnt;
        const unsigned entry = valid ? buf[i] : 0u;
        const int d  = entry & 0xFFFFu;
        const int sl = entry >> 16;
        float t = asl[sl] + a_dstv[d];
        t = t > 0.f ? t : ALPHA_ * t;
        const float w = valid ? __expf(t) : 0.f;   // w=0 => contributes nothing
        zacc += w;
        #pragma unroll 8
        for (int j = 0; j < 64; ++j) {
            const float wj = __shfl(w, j);
            const int   dj = __shfl(d, j);
            const int   sj = __shfl(sl, j);
            const float hv = h[(size_t)dj * OUT_DIM_ + lane];
            atomicAdd(&accs[sj][lane], wj * hv);
        }
    }

    #pragma unroll
    for (int m = 32; m; m >>= 1) zacc += __shfl_xor(zacc, m);
    if (lane == 0) zred[wid] = zacc;
    __syncthreads();
    if (tid == 0) atomicAdd(Z, zred[0] + zred[1] + zred[2] + zred[3]);

    const int rows_here = min(PNODES, N_NODES - n0);
    for (int i = tid; i < rows_here * (OUT_DIM_ / 4); i += 256) {
        const int r  = i >> 4;          // / (OUT_DIM_/4)
        const int c4 = i & 15;
        *(float4*)&out[(size_t)(n0 + r) * OUT_DIM_ + c4 * 4] =
            *(const float4*)&accs[r][c4 * 4];
    }
}

// ---------------------------------------------------------------------------
// Kernel 4: overflow fix (cap-exceeded edges). Empty in practice; guarantees
// correctness for any input. Runs AFTER gather (plain stores), BEFORE finalize.
// ---------------------------------------------------------------------------
__global__ __launch_bounds__(256) void ovf_fix(const int* __restrict__ ovf_cnt,
                                               const int2* __restrict__ ovf,
                                               const float* __restrict__ a_srcv,
                                               const float* __restrict__ a_dstv,
                                               const float* __restrict__ h,
                                               float* __restrict__ out) {
    const int nov = min(*ovf_cnt, OVF_CAP);
    const int lane = threadIdx.x & 63;
    const int wid = (blockIdx.x * 256 + threadIdx.x) >> 6;
    const int nw = (gridDim.x * 256) >> 6;
    for (int i = wid; i < nov; i += nw) {
        const int2 sd = ovf[i];
        float t = a_srcv[sd.x] + a_dstv[sd.y];
        t = t > 0.f ? t : ALPHA_ * t;
        const float val = __expf(t);
        atomicAdd(&out[(size_t)sd.x * OUT_DIM_ + lane], val * h[(size_t)sd.y * OUT_DIM_ + lane]);
    }
}

// ---------------------------------------------------------------------------
// Kernel 5: out = elu(out / Z), in place, float4.
// ---------------------------------------------------------------------------
__global__ __launch_bounds__(256) void finalize(float* __restrict__ out,
                                                const float* __restrict__ Z) {
    const float inv = 1.0f / *Z;
    const int total4 = N_NODES * OUT_DIM_ / 4;
    const int stride = gridDim.x * 256;
    for (int idx = blockIdx.x * 256 + threadIdx.x; idx < total4; idx += stride) {
        float4 v = ((float4*)out)[idx];
        float u;
        u = v.x * inv; v.x = u > 0.f ? u : expm1f(u);
        u = v.y * inv; v.y = u > 0.f ? u : expm1f(u);
        u = v.z * inv; v.z = u > 0.f ? u : expm1f(u);
        u = v.w * inv; v.w = u > 0.f ? u : expm1f(u);
        ((float4*)out)[idx] = v;
    }
}

// ---------------------------------------------------------------------------
extern "C" void kernel_launch(void* const* d_in, const int* in_sizes, int n_in,
                              void* d_out, int out_size, void* d_ws, size_t ws_size,
                              hipStream_t stream) {
    const float* x  = (const float*)d_in[0];
    const float* W  = (const float*)d_in[1];
    const float* a  = (const float*)d_in[2];
    const int*   ei = (const int*)d_in[3];
    float* out = (float*)d_out;

    // ws layout (4B units):
    //   h[N*64] | a_srcv[N] | a_dstv[N] | part_buf[NPART*CAPP] |
    //   ovf[OVF_CAP*2] | part_cnt[NPART] | Z | ovf_cnt
    float* ws       = (float*)d_ws;
    float* h        = ws;
    float* a_srcv   = h + (size_t)N_NODES * OUT_DIM_;
    float* a_dstv   = a_srcv + N_NODES;
    unsigned int* part_buf = (unsigned int*)(a_dstv + N_NODES);
    int2*  ovf      = (int2*)(part_buf + (size_t)NPART * CAPP);
    int*   part_cnt = (int*)(ovf + OVF_CAP);
    float* Z        = (float*)(part_cnt + NPART);
    int*   ovfc     = (int*)(Z + 1);

    hipMemsetAsync(part_cnt, 0, (NPART + 2) * sizeof(int), stream);

    gemm_h<<<(N_NODES + 63) / 64, 256, 0, stream>>>(x, W, a, h, a_srcv, a_dstv);
    bin_edges<<<BIN_BLOCKS, 256, 0, stream>>>(ei, part_cnt, part_buf, ovfc, ovf);
    gather_accum<<<NPART, 256, 0, stream>>>(part_cnt, part_buf, a_srcv, a_dstv, h, out, Z);
    ovf_fix<<<32, 256, 0, stream>>>(ovfc, ovf, a_srcv, a_dstv, h, out);
    finalize<<<1024, 256, 0, stream>>>(out, Z);
}

// Round 5
// 463.166 us; speedup vs baseline: 1.0889x; 1.0889x over previous
//
#include <hip/hip_runtime.h>
#include <hip/hip_bf16.h>
#include <math.h>

#define N_NODES 50000
#define N_EDGES 800000
#define IN_DIM_ 128
#define OUT_DIM_ 64
#define ALPHA_ 0.2f

#define PSH 6                 // 64 src-nodes per partition
#define PNODES 64
#define NPART 782             // ceil(50000/64)
#define CAPP 2048             // per-partition capacity; mean 1024, +32 sigma
#define BIN_BLOCKS 256
#define BIN_CHUNK ((N_EDGES + BIN_BLOCKS - 1) / BIN_BLOCKS)   // 3125
#define OVF_CAP 8192          // never used in practice; correctness guard

// ---------------------------------------------------------------------------
// Kernel 1: h = x @ W  (M=50000, K=128, N=64) fp32 vector GEMM, with the
// node-score epilogue fused: a_src[n] = h[n]·a[:64], a_dst[n] = h[n]·a[64:].
// ---------------------------------------------------------------------------
__global__ __launch_bounds__(256, 4) void gemm_h(const float* __restrict__ x,
                                                 const float* __restrict__ W,
                                                 const float* __restrict__ a_g,
                                                 float* __restrict__ h,
                                                 float* __restrict__ a_srcv,
                                                 float* __restrict__ a_dstv) {
    __shared__ float At[64][68];  // [kk][row]
    __shared__ float Wl[64][68];  // [kk][col]
    const int tid = threadIdx.x;
    const int tx = tid & 15;      // col group (4 cols)
    const int ty = tid >> 4;      // row group (4 rows)
    const int row0 = blockIdx.x * 64;

    float acc[4][4] = {};

    for (int ks = 0; ks < 128; ks += 64) {
        {
            const int r  = tid >> 4;   // 0..15
            const int k4 = tid & 15;   // float4 index along k
            #pragma unroll
            for (int rr = 0; rr < 64; rr += 16) {
                const int row = row0 + r + rr;
                float4 v = make_float4(0.f, 0.f, 0.f, 0.f);
                if (row < N_NODES)
                    v = *(const float4*)&x[(size_t)row * IN_DIM_ + ks + k4 * 4];
                At[k4 * 4 + 0][r + rr] = v.x;
                At[k4 * 4 + 1][r + rr] = v.y;
                At[k4 * 4 + 2][r + rr] = v.z;
                At[k4 * 4 + 3][r + rr] = v.w;
            }
            const int kr = tid >> 4;
            const int c4 = tid & 15;
            #pragma unroll
            for (int kk = 0; kk < 64; kk += 16) {
                float4 wv = *(const float4*)&W[(size_t)(ks + kr + kk) * OUT_DIM_ + c4 * 4];
                *(float4*)&Wl[kr + kk][c4 * 4] = wv;
            }
        }
        __syncthreads();

        #pragma unroll 16
        for (int kk = 0; kk < 64; ++kk) {
            const float4 a4 = *(const float4*)&At[kk][ty * 4];
            const float4 b4 = *(const float4*)&Wl[kk][tx * 4];
            acc[0][0] += a4.x * b4.x; acc[0][1] += a4.x * b4.y; acc[0][2] += a4.x * b4.z; acc[0][3] += a4.x * b4.w;
            acc[1][0] += a4.y * b4.x; acc[1][1] += a4.y * b4.y; acc[1][2] += a4.y * b4.z; acc[1][3] += a4.y * b4.w;
            acc[2][0] += a4.z * b4.x; acc[2][1] += a4.z * b4.y; acc[2][2] += a4.z * b4.z; acc[2][3] += a4.z * b4.w;
            acc[3][0] += a4.w * b4.x; acc[3][1] += a4.w * b4.y; acc[3][2] += a4.w * b4.z; acc[3][3] += a4.w * b4.w;
        }
        __syncthreads();
    }

    const float a0 = a_g[tx * 4 + 0], a1 = a_g[tx * 4 + 1];
    const float a2 = a_g[tx * 4 + 2], a3 = a_g[tx * 4 + 3];
    const float b0 = a_g[64 + tx * 4 + 0], b1 = a_g[64 + tx * 4 + 1];
    const float b2 = a_g[64 + tx * 4 + 2], b3 = a_g[64 + tx * 4 + 3];

    #pragma unroll
    for (int i = 0; i < 4; ++i) {
        const int row = row0 + ty * 4 + i;
        if (row < N_NODES) {
            float4 o = make_float4(acc[i][0], acc[i][1], acc[i][2], acc[i][3]);
            *(float4*)&h[(size_t)row * OUT_DIM_ + tx * 4] = o;
        }
        float s = acc[i][0] * a0 + acc[i][1] * a1 + acc[i][2] * a2 + acc[i][3] * a3;
        float d = acc[i][0] * b0 + acc[i][1] * b1 + acc[i][2] * b2 + acc[i][3] * b3;
        #pragma unroll
        for (int m = 1; m < 16; m <<= 1) {
            s += __shfl_xor(s, m);
            d += __shfl_xor(d, m);
        }
        if (tx == 0 && row < N_NODES) {
            a_srcv[row] = s;
            a_dstv[row] = d;
        }
    }
}

// ---------------------------------------------------------------------------
// Kernel 2: bin edges by src-partition (64 nodes/partition).
// Per block: LDS histogram (fire-and-forget LDS atomics) -> ONE global
// atomicAdd per non-empty partition to reserve a contiguous range -> place
// each edge via LDS atomic-with-return (cheap) + 4B packed write.
// Packing: entry = (s&63)<<16 | d   (d < 50000 < 2^16).
// ---------------------------------------------------------------------------
__global__ __launch_bounds__(256) void bin_edges(const int* __restrict__ ei,
                                                 int* __restrict__ part_cnt,
                                                 unsigned int* __restrict__ part_buf,
                                                 int* __restrict__ ovf_cnt,
                                                 int2* __restrict__ ovf) {
    __shared__ int hist[NPART];
    __shared__ int cur[NPART];
    const int tid = threadIdx.x;
    const int e0 = blockIdx.x * BIN_CHUNK;
    const int e1 = min(e0 + BIN_CHUNK, N_EDGES);

    for (int p = tid; p < NPART; p += 256) hist[p] = 0;
    __syncthreads();

    for (int e = e0 + tid; e < e1; e += 256) {
        atomicAdd(&hist[ei[e] >> PSH], 1);
    }
    __syncthreads();

    for (int p = tid; p < NPART; p += 256) {
        const int c = hist[p];
        cur[p] = (c > 0) ? atomicAdd(&part_cnt[p], c) : 0;
    }
    __syncthreads();

    for (int e = e0 + tid; e < e1; e += 256) {
        const int s = ei[e];
        const int d = ei[N_EDGES + e];
        const int p = s >> PSH;
        const int slot = atomicAdd(&cur[p], 1);   // LDS rtn atomic: cheap
        if (slot < CAPP) {
            part_buf[(size_t)p * CAPP + slot] =
                ((unsigned)(s & (PNODES - 1)) << 16) | (unsigned)d;
        } else {
            const int o = atomicAdd(ovf_cnt, 1);
            if (o < OVF_CAP) ovf[o] = make_int2(s, d);
        }
    }
}

// ---------------------------------------------------------------------------
// Kernel 3: per-partition gather-accumulate into a 64x65 LDS tile.
// ONE EDGE PER LANE (round-4's per-wave broadcast was the 391us mistake:
// 3-dependent-shuffle chain + 1 cache line in flight per wave).
// Per lane: weight from node scores (parallel), then 16 independent float4
// loads of its h[dst] row (64 scattered 16B segments/instr -> high MLP) and
// 64 fire-and-forget ds_add_f32 into accs[sl][c]. Stride 65 => bank =
// (sl+c)&31: random sl over 64 values ~ 2 lanes/bank (free). Z fused.
// One coalesced 16KB store per block. Zero global atomics.
// ---------------------------------------------------------------------------
__global__ __launch_bounds__(256) void gather_accum(const int* __restrict__ part_cnt,
                                                    const unsigned int* __restrict__ part_buf,
                                                    const float* __restrict__ a_srcv,
                                                    const float* __restrict__ a_dstv,
                                                    const float* __restrict__ h,
                                                    float* __restrict__ out,
                                                    float* __restrict__ Z) {
    __shared__ float accs[PNODES][PNODES + 1];   // 16.25 KB, pad kills bank conflicts
    __shared__ float asl[PNODES];
    __shared__ float zred[4];
    const int p = blockIdx.x;
    const int tid = threadIdx.x;
    const int lane = tid & 63;
    const int wid = tid >> 6;
    const int n0 = p << PSH;

    for (int i = tid; i < PNODES * (PNODES + 1); i += 256)
        (&accs[0][0])[i] = 0.f;
    if (tid < PNODES)
        asl[tid] = (n0 + tid < N_NODES) ? a_srcv[n0 + tid] : 0.f;
    __syncthreads();

    const int cnt = min(part_cnt[p], CAPP);
    const unsigned int* __restrict__ buf = part_buf + (size_t)p * CAPP;
    float zacc = 0.f;

    for (int i = tid; i < cnt; i += 256) {
        const unsigned entry = buf[i];
        const int d  = entry & 0xFFFFu;
        const int sl = entry >> 16;
        float t = asl[sl] + a_dstv[d];
        t = t > 0.f ? t : ALPHA_ * t;
        const float w = __expf(t);
        zacc += w;
        const float4* __restrict__ hp = (const float4*)&h[(size_t)d * OUT_DIM_];
        #pragma unroll
        for (int c4 = 0; c4 < 16; ++c4) {
            const float4 hv = hp[c4];
            atomicAdd(&accs[sl][c4 * 4 + 0], w * hv.x);
            atomicAdd(&accs[sl][c4 * 4 + 1], w * hv.y);
            atomicAdd(&accs[sl][c4 * 4 + 2], w * hv.z);
            atomicAdd(&accs[sl][c4 * 4 + 3], w * hv.w);
        }
    }

    #pragma unroll
    for (int m = 32; m; m >>= 1) zacc += __shfl_xor(zacc, m);
    if (lane == 0) zred[wid] = zacc;
    __syncthreads();
    if (tid == 0) atomicAdd(Z, zred[0] + zred[1] + zred[2] + zred[3]);

    const int rows_here = min(PNODES, N_NODES - n0);
    for (int i = tid; i < rows_here * (OUT_DIM_ / 4); i += 256) {
        const int r  = i >> 4;          // / (OUT_DIM_/4)
        const int c4 = i & 15;
        *(float4*)&out[(size_t)(n0 + r) * OUT_DIM_ + c4 * 4] =
            *(const float4*)&accs[r][c4 * 4];
    }
}

// ---------------------------------------------------------------------------
// Kernel 4: overflow fix (cap-exceeded edges). Empty in practice; guarantees
// correctness for any input. Runs AFTER gather (plain stores), BEFORE finalize.
// ---------------------------------------------------------------------------
__global__ __launch_bounds__(256) void ovf_fix(const int* __restrict__ ovf_cnt,
                                               const int2* __restrict__ ovf,
                                               const float* __restrict__ a_srcv,
                                               const float* __restrict__ a_dstv,
                                               const float* __restrict__ h,
                                               float* __restrict__ out) {
    const int nov = min(*ovf_cnt, OVF_CAP);
    const int lane = threadIdx.x & 63;
    const int wid = (blockIdx.x * 256 + threadIdx.x) >> 6;
    const int nw = (gridDim.x * 256) >> 6;
    for (int i = wid; i < nov; i += nw) {
        const int2 sd = ovf[i];
        float t = a_srcv[sd.x] + a_dstv[sd.y];
        t = t > 0.f ? t : ALPHA_ * t;
        const float val = __expf(t);
        atomicAdd(&out[(size_t)sd.x * OUT_DIM_ + lane], val * h[(size_t)sd.y * OUT_DIM_ + lane]);
    }
}

// ---------------------------------------------------------------------------
// Kernel 5: out = elu(out / Z), in place, float4.
// ---------------------------------------------------------------------------
__global__ __launch_bounds__(256) void finalize(float* __restrict__ out,
                                                const float* __restrict__ Z) {
    const float inv = 1.0f / *Z;
    const int total4 = N_NODES * OUT_DIM_ / 4;
    const int stride = gridDim.x * 256;
    for (int idx = blockIdx.x * 256 + threadIdx.x; idx < total4; idx += stride) {
        float4 v = ((float4*)out)[idx];
        float u;
        u = v.x * inv; v.x = u > 0.f ? u : expm1f(u);
        u = v.y * inv; v.y = u > 0.f ? u : expm1f(u);
        u = v.z * inv; v.z = u > 0.f ? u : expm1f(u);
        u = v.w * inv; v.w = u > 0.f ? u : expm1f(u);
        ((float4*)out)[idx] = v;
    }
}

// ---------------------------------------------------------------------------
extern "C" void kernel_launch(void* const* d_in, const int* in_sizes, int n_in,
                              void* d_out, int out_size, void* d_ws, size_t ws_size,
                              hipStream_t stream) {
    const float* x  = (const float*)d_in[0];
    const float* W  = (const float*)d_in[1];
    const float* a  = (const float*)d_in[2];
    const int*   ei = (const int*)d_in[3];
    float* out = (float*)d_out;

    // ws layout (4B units):
    //   h[N*64] | a_srcv[N] | a_dstv[N] | part_buf[NPART*CAPP] |
    //   ovf[OVF_CAP*2] | part_cnt[NPART] | Z | ovf_cnt
    float* ws       = (float*)d_ws;
    float* h        = ws;
    float* a_srcv   = h + (size_t)N_NODES * OUT_DIM_;
    float* a_dstv   = a_srcv + N_NODES;
    unsigned int* part_buf = (unsigned int*)(a_dstv + N_NODES);
    int2*  ovf      = (int2*)(part_buf + (size_t)NPART * CAPP);
    int*   part_cnt = (int*)(ovf + OVF_CAP);
    float* Z        = (float*)(part_cnt + NPART);
    int*   ovfc     = (int*)(Z + 1);

    hipMemsetAsync(part_cnt, 0, (NPART + 2) * sizeof(int), stream);

    gemm_h<<<(N_NODES + 63) / 64, 256, 0, stream>>>(x, W, a, h, a_srcv, a_dstv);
    bin_edges<<<BIN_BLOCKS, 256, 0, stream>>>(ei, part_cnt, part_buf, ovfc, ovf);
    gather_accum<<<NPART, 256, 0, stream>>>(part_cnt, part_buf, a_srcv, a_dstv, h, out, Z);
    ovf_fix<<<32, 256, 0, stream>>>(ovfc, ovf, a_srcv, a_dstv, h, out);
    finalize<<<1024, 256, 0, stream>>>(out, Z);
}